// Round 16
// baseline (12432.558 us; speedup 1.0000x reference)
//
#include <hip/hip_runtime.h>

// BiRNN: B=128, S=512, E=512, H=1024, V=50000, C=2
// Persistent cooperative kernel, 256 blocks (1 per CU, forced by 160KB LDS).
// XCD-SELF-ORGANIZED split-K (round 12): block claims a slot on its physical
// XCD; 28 roles/XCD (2 h0 tiles x 6 chunks + 2 h1 tiles x 8 chunks); slots
// 28..31 EXIT. Partials: NORMAL stores -> local L2; sc0 loads (L2-served).
// Cross-XCD h state: relaxed agent-scope sc1 (LLC). Weights LDS-resident.
// Sync (round 15): per-TILE barrier-1 (fan-in 6/8) + per-DIRECTION two-level
// barrier-2 (28/XCD -> 4 -> flag). A-stage double-buffered, 8 syncs/phase.
// NEW (round 16): embedding gather loads are NON-TEMPORAL
// (__builtin_nontemporal_load) -> gather lines no longer churn the XCD L2,
// dirty partial lines stop evicting to HBM (round-15 counters: 15.2MB/phase
// WRITE vs 2MB payload), REDUCE partial reads stay L2-hit.

#define S_LEN 512

typedef short bf16x8 __attribute__((ext_vector_type(8)));
typedef float f32x4 __attribute__((ext_vector_type(4)));
typedef unsigned int u32x4 __attribute__((ext_vector_type(4)));

__device__ __forceinline__ unsigned short f2bf(float f) {
    unsigned u = __float_as_uint(f);
    u += 0x7fff + ((u >> 16) & 1);
    return (unsigned short)(u >> 16);
}
__device__ __forceinline__ float bf2f(unsigned short h) {
    return __uint_as_float(((unsigned)h) << 16);
}
__device__ __forceinline__ f32x4 mfma16(bf16x8 a, bf16x8 b, f32x4 c) {
    return __builtin_amdgcn_mfma_f32_16x16x32_bf16(a, b, c, 0, 0, 0);
}
// relaxed agent-scope (sc1 -> LLC) accesses for cross-XCD state
__device__ __forceinline__ unsigned long long ld8_cc(const void* p) {
    return __hip_atomic_load((unsigned long long*)p, __ATOMIC_RELAXED,
                             __HIP_MEMORY_SCOPE_AGENT);
}
__device__ __forceinline__ void st4_cc(void* p, float v) {
    __hip_atomic_store((int*)p, __float_as_int(v), __ATOMIC_RELAXED,
                       __HIP_MEMORY_SCOPE_AGENT);
}
// 16B sc1 store (full-line h writes, round 14). NOT compiler-tracked ->
// explicit vmcnt drain before dependent barrier (rule #18 analog).
__device__ __forceinline__ void st16_cc(void* p, u32x4 v) {
    asm volatile("global_store_dwordx4 %0, %1, off sc1"
                 :: "v"(p), "v"(v) : "memory");
}

union U8  { unsigned long long u; float f[2]; unsigned short s[4]; };
union F16 { bf16x8 v; unsigned long long u[2]; unsigned short s[8]; };

// ws layout (bytes):
//  part @ 0          : [32 tile][8 chunk][16384 f32 frag-linear] = 16,777,216
//  Hx   @ 16,777,216 : 8 slices x [128 row][128 kb][hi8|lo8] us = 4,194,304
//  Hfin @ 20,971,520 : [2 dir][128][1024] f32 = 1,048,576
//  tcnt @ 22,020,096 : 32 x 64B (per-tile barrier-1 counters)
//  xcnt @ 22,022,144 : 8 x 64B  (per-XCD barrier-2 arrivals)
//  dl2c @ 22,022,656 : 2 x 64B  (per-dir second level)
//  dflg @ 22,022,784 : 2 x 64B  (per-dir release flags)
//  xcdc @ 22,022,912 : 8 x 64B  (claim counters)
//  fc1  @ 22,024,192 : 32,768

__global__ __launch_bounds__(512) void rnn_persist(
    const int* __restrict__ x, const float* __restrict__ emb,
    const float* __restrict__ f0Wi, const float* __restrict__ f0Wh,
    const float* __restrict__ f1Wi, const float* __restrict__ f1Wh,
    const float* __restrict__ b0Wi, const float* __restrict__ b0Wh,
    const float* __restrict__ b1Wi, const float* __restrict__ b1Wh,
    const float* __restrict__ f0bi, const float* __restrict__ f0bh,
    const float* __restrict__ f1bi, const float* __restrict__ f1bh,
    const float* __restrict__ b0bi, const float* __restrict__ b0bh,
    const float* __restrict__ b1bi, const float* __restrict__ b1bh,
    unsigned short* __restrict__ Hx, float* __restrict__ part,
    int* __restrict__ tcnt, int* __restrict__ xcnt, int* __restrict__ dl2c,
    int* __restrict__ dflg, int* __restrict__ xcdc, float* __restrict__ Hfin)
{
    // LDS (ushort idx): [0,32768) W-hi  [32768,65536) W-lo  (frag order)
    //   stage buf b: hi @ 65536+b*8192, lo @ 69632+b*8192  (b=0,1)
    //   reduce bounce reuses buf0 region (first 2048 of hi/lo)
    __shared__ unsigned short lds[81920];   // 160 KiB exactly -> 1 block/CU

    const int tid = threadIdx.x;

    // ---- self-organized role claim on this block's physical XCD ----
    int xcc;
    asm volatile("s_getreg_b32 %0, hwreg(HW_REG_XCC_ID)" : "=s"(xcc));
    xcc &= 7;
    if (tid == 0)
        ((volatile int*)lds)[0] =
            __hip_atomic_fetch_add(xcdc + xcc * 16, 1,
                                   __ATOMIC_RELAXED, __HIP_MEMORY_SCOPE_AGENT);
    __syncthreads();
    const int slot = ((volatile int*)lds)[0];
    __syncthreads();            // all read slot before weights overwrite lds[0]
    if (slot >= 28) return;     // 4 idle blocks/XCD exit (barriers sized 28)

    int tileid, chunk;
    if (slot < 12) { tileid = xcc * 2 + (slot >= 6 ? 1 : 0); chunk = slot % 6; }
    else           { tileid = 16 + xcc * 2 + (slot >= 20 ? 1 : 0); chunk = (slot - 12) & 7; }
    const bool isH0 = tileid < 16;
    int dir, stripe;
    if (isH0) { dir = tileid >> 3; stripe = tileid & 7; }
    else      { int u = tileid - 16; dir = u >> 3; stripe = 8 + (u & 7); }
    const int dirg = xcc >> 2;      // barrier-2 group (== dir by mapping)

    const bool eg = isH0 && (chunk < 2);
    const int nparts = isH0 ? 6 : 8;
    const int cstart = (stripe & 7) * 128;
    const int tile = dir * 16 + stripe;
    const int hout = isH0 ? 0 : 1;

    const float* Wsrc = f0Wi; int koffw = 0; int hselA = 0;
    if (isH0) {
        if (eg) { Wsrc = dir ? b0Wi : f0Wi; koffw = chunk * 256; }
        else    { Wsrc = dir ? b0Wh : f0Wh; koffw = chunk * 256 - 512; }
    } else {
        if (chunk < 4) { Wsrc = dir ? b1Wi : f1Wi; koffw = chunk * 256;        hselA = 0; }
        else           { Wsrc = dir ? b1Wh : f1Wh; koffw = chunk * 256 - 1024; hselA = 1; }
    }
    const float *bA, *bB;
    if (isH0) { bA = dir ? b0bi : f0bi; bB = dir ? b0bh : f0bh; }
    else      { bA = dir ? b1bi : f1bi; bB = dir ? b1bh : f1bh; }

    // ---- one-time: weight tile -> LDS (hi/lo, frag order) ----
    for (int q = tid; q < 32768; q += 512) {
        int k = q >> 7, c = q & 127;
        float w = Wsrc[(size_t)(koffw + k) * 1024 + cstart + c];
        unsigned short h = f2bf(w);
        int o = ((k >> 3) * 128 + c) * 8 + (k & 7);
        lds[o] = h;
        lds[32768 + o] = f2bf(w - bf2f(h));
    }

    const int lane = tid & 63, wid = tid >> 6;
    const int wm = (wid >> 2) * 64, wn = (wid & 3) * 32;
    const int lrow = lane & 15, kgrp = lane >> 4;
    const int srow = tid >> 2;          // stager row 0..127
    const int skq  = tid & 3;           // stager k-quarter
    const int sk   = skq * 8;

    float* myPart = part + (size_t)(tile * 8 + chunk) * 16384;
    const float* pb = part + (size_t)tile * 8 * 16384;

    // reduce subtile assignment (h1: chunk<->wave; h0: 6 chunks cover 8)
    int ns, wsl0, wsl1 = 0;
    if (!isH0 || chunk < 4) { ns = 1; wsl0 = chunk; }
    else { ns = 2; wsl0 = 4 + (chunk - 4) * 2; wsl1 = wsl0 + 1; }

// eg path: NON-TEMPORAL loads (no L2 allocation churn; compiler-tracked)
#define ISSUE(sl, sv)                                                          \
    do { if (eg) {                                                             \
            const float* ep_ = erow + (sv) * 32;                               \
            e0[sl] = __builtin_nontemporal_load((const f32x4*)(ep_));          \
            e1[sl] = __builtin_nontemporal_load((const f32x4*)(ep_ + 4));      \
        } else {                                                               \
            gh[sl].u[0] = ld8_cc(aB + (sv) * 64);                              \
            gh[sl].u[1] = ld8_cc(aB + (sv) * 64 + 4);                          \
            gl[sl].u[0] = ld8_cc(aB + (sv) * 64 + 8);                          \
            gl[sl].u[1] = ld8_cc(aB + (sv) * 64 + 12);                         \
        } } while (0)

#define STAGE(sl, b)                                                           \
    do { int ao_ = (skq * 128 + srow) * 8 + (b) * 8192;                        \
        if (eg) {                                                              \
            F16 hh_, ll_;                                                      \
            float ev_[8] = {e0[sl][0], e0[sl][1], e0[sl][2], e0[sl][3],        \
                            e1[sl][0], e1[sl][1], e1[sl][2], e1[sl][3]};       \
            _Pragma("unroll") for (int j_ = 0; j_ < 8; ++j_) {                 \
                unsigned short h_ = f2bf(ev_[j_]);                             \
                hh_.s[j_] = h_; ll_.s[j_] = f2bf(ev_[j_] - bf2f(h_)); }        \
            *(bf16x8*)&lds[65536 + ao_] = hh_.v;                               \
            *(bf16x8*)&lds[69632 + ao_] = ll_.v;                               \
        } else {                                                               \
            *(bf16x8*)&lds[65536 + ao_] = gh[sl].v;                            \
            *(bf16x8*)&lds[69632 + ao_] = gl[sl].v; } } while (0)

#define CONSUME(sv, b)                                                         \
    do { bf16x8 bh_[2], bl_[2];                                                \
        _Pragma("unroll") for (int jj_ = 0; jj_ < 2; ++jj_) {                  \
            int bo_ = (((sv) * 4 + kgrp) * 128 + wn + jj_ * 16 + lrow) * 8;    \
            bh_[jj_] = *(const bf16x8*)&lds[bo_];                              \
            bl_[jj_] = *(const bf16x8*)&lds[32768 + bo_]; }                    \
        _Pragma("unroll") for (int i_ = 0; i_ < 4; ++i_) {                     \
            int ao_ = (kgrp * 128 + wm + i_ * 16 + lrow) * 8 + (b) * 8192;     \
            bf16x8 ah_ = *(const bf16x8*)&lds[65536 + ao_];                    \
            bf16x8 al_ = *(const bf16x8*)&lds[69632 + ao_];                    \
            _Pragma("unroll") for (int jj_ = 0; jj_ < 2; ++jj_) {              \
                acc[i_][jj_] = mfma16(ah_, bh_[jj_], acc[i_][jj_]);            \
                acc[i_][jj_] = mfma16(ah_, bl_[jj_], acc[i_][jj_]);            \
                acc[i_][jj_] = mfma16(al_, bh_[jj_], acc[i_][jj_]); } } } while (0)

// partials are XCD-local: sc0 loads (L1-bypass, L2-served) see the dirty L2
// lines written by same-XCD producers (proven round 12).
// h store: one 16B sc1 store/thread, lane-consecutive (round 14).
#define REDUCE(NP)                                                             \
    do { unsigned short* dst = Hx + (size_t)((hout * 2 + dir) * 2 + wp) * 262144; \
        unsigned short* bh = &lds[65536];                                      \
        unsigned short* bl = &lds[69632];                                      \
        for (int si = 0; si < ns; ++si) {                                      \
            int ws_ = si ? wsl1 : wsl0;                                        \
            int q = ws_ * 512 + tid;                                           \
            const float* p0 = pb + (size_t)q * 4;                              \
            float4 pv[NP];                                                     \
            _Pragma("unroll") for (int c_ = 0; c_ < (NP); ++c_)                \
                asm volatile("global_load_dwordx4 %0, %1, off sc0"             \
                             : "=v"(pv[c_])                                    \
                             : "v"(p0 + (size_t)c_ * 16384) : "memory");       \
            asm volatile("s_waitcnt vmcnt(0)" ::: "memory");                   \
            __builtin_amdgcn_sched_barrier(0);                                 \
            float s0 = 0.f, s1 = 0.f, s2 = 0.f, s3 = 0.f;                      \
            _Pragma("unroll") for (int c_ = 0; c_ < (NP); ++c_) {              \
                s0 += pv[c_].x; s1 += pv[c_].y;                                \
                s2 += pv[c_].z; s3 += pv[c_].w; }                              \
            int t_ = ws_ * 8 + (tid >> 6);                                     \
            int ii_ = (t_ & 7) >> 1, jj_ = t_ & 1, ln_ = tid & 63;             \
            int colj = jj_ * 16 + (ln_ & 15);                                  \
            int gc = cstart + (ws_ & 3) * 32 + colj;                           \
            float bsum = bA[gc] + bB[gc];                                      \
            int rsb = ii_ * 16 + (ln_ >> 4) * 4;                               \
            float vv_[4] = {s0 + bsum, s1 + bsum, s2 + bsum, s3 + bsum};       \
            _Pragma("unroll") for (int r_ = 0; r_ < 4; ++r_) {                 \
                float v_ = tanhf(vv_[r_]);                                     \
                unsigned short h_ = f2bf(v_);                                  \
                bh[(rsb + r_) * 32 + colj] = h_;                               \
                bl[(rsb + r_) * 32 + colj] = f2bf(v_ - bf2f(h_));              \
                if (fin)                                                       \
                    st4_cc(Hfin + (size_t)dir * 131072 +                       \
                           (size_t)((ws_ >> 2) * 64 + rsb + r_) * 1024 + gc, v_); \
            }                                                                  \
            __syncthreads();                                                   \
            {                                                                  \
                int half_ = tid & 1, kbl_ = (tid >> 1) & 3, rs2_ = tid >> 3;   \
                int row_g = (ws_ >> 2) * 64 + rs2_;                            \
                int kb_g = ((cstart + (ws_ & 3) * 32) >> 3) + kbl_;            \
                const unsigned short* sp_ = (half_ ? bl : bh)                  \
                                          + rs2_ * 32 + kbl_ * 8;              \
                unsigned short* dp = dst + (size_t)row_g * 2048                \
                                   + kb_g * 16 + half_ * 8;                    \
                st16_cc(dp, *(const u32x4*)sp_);                               \
            }                                                                  \
            asm volatile("s_waitcnt vmcnt(0)" ::: "memory");                   \
            __syncthreads();                                                   \
        } } while (0)

    int tep = 0;                        // per-tile active-epoch (barrier-1)
    for (int p = 0; p <= S_LEN; ++p) {
        const bool act = isH0 ? (p < S_LEN) : (p > 0);
        const int rp = (p + 1) & 1, wp = p & 1;

        if (act) {
            // ---- GEMM: 128x128 tile over this block's 256-k chunk ----
            const unsigned short* aB = Hx;
            const float* erow = emb;
            if (eg) {
                int tsel = dir ? (S_LEN - 1 - p) : p;
                int idx = x[srow * S_LEN + tsel];
                erow = emb + (size_t)idx * 512 + koffw + sk;
            } else {
                aB = Hx + (size_t)((hselA * 2 + dir) * 2 + rp) * 262144
                   + (size_t)srow * 2048 + ((koffw >> 3) + skq) * 16;
            }

            f32x4 acc[4][2];
            #pragma unroll
            for (int i = 0; i < 4; ++i)
                #pragma unroll
                for (int j = 0; j < 2; ++j) acc[i][j] = (f32x4){0.f, 0.f, 0.f, 0.f};

            f32x4 e0[3], e1[3];
            F16 gh[3], gl[3];
            ISSUE(0, 0); ISSUE(1, 1); ISSUE(2, 2);
            #pragma unroll
            for (int s = 0; s < 8; ++s) {
                const int sl = s % 3;               // static under full unroll
                const int b  = s & 1;               // double-buffered stage
                STAGE(sl, b);                       // prev buf-b use ended at
                __syncthreads();                    //   sync(s-1) -> WAR safe
                if (s < 5) ISSUE(sl, s + 3);        // refill, 3 ahead
                CONSUME(s, b);
            }

            // frag-linear partial store, NORMAL stores -> local-XCD L2 only
            #pragma unroll
            for (int i = 0; i < 4; ++i)
                #pragma unroll
                for (int jj = 0; jj < 2; ++jj) {
                    int q = (wid * 8 + i * 2 + jj) * 64 + lane;
                    *(float4*)(myPart + (size_t)q * 4) =
                        make_float4(acc[i][jj][0], acc[i][jj][1],
                                    acc[i][jj][2], acc[i][jj][3]);
                }

            // ---- barrier-1: per-tile (fan-in nparts, agent/LLC) ----
            ++tep;
            __syncthreads();   // drains vmcnt -> partial stores committed to L2
            if (tid == 0) {
                __hip_atomic_fetch_add(tcnt + tile * 16, 1,
                                       __ATOMIC_RELAXED, __HIP_MEMORY_SCOPE_AGENT);
                while (__hip_atomic_load(tcnt + tile * 16, __ATOMIC_RELAXED,
                                         __HIP_MEMORY_SCOPE_AGENT) < tep * nparts) { }
            }
            __syncthreads();

            const bool fin = (!isH0) && (p == S_LEN);
            if (isH0) REDUCE(6); else REDUCE(8);
        }

        // ---- barrier-2: per-direction (28/XCD -> 4 XCDs -> flag) ----
        {
            const int ep2 = p + 1;
            __syncthreads();   // drains vmcnt -> sc1 h stores LLC-acked
            if (tid == 0) {
                int old = __hip_atomic_fetch_add(xcnt + xcc * 16, 1,
                                                 __ATOMIC_RELAXED,
                                                 __HIP_MEMORY_SCOPE_AGENT);
                if (old == ep2 * 28 - 1) {
                    int old2 = __hip_atomic_fetch_add(dl2c + dirg * 16, 1,
                                                      __ATOMIC_RELAXED,
                                                      __HIP_MEMORY_SCOPE_AGENT);
                    if (old2 == ep2 * 4 - 1)
                        __hip_atomic_store(dflg + dirg * 16, ep2,
                                           __ATOMIC_RELAXED,
                                           __HIP_MEMORY_SCOPE_AGENT);
                }
                while (__hip_atomic_load(dflg + dirg * 16, __ATOMIC_RELAXED,
                                         __HIP_MEMORY_SCOPE_AGENT) < ep2)
                    __builtin_amdgcn_s_sleep(1);
            }
            __syncthreads();
        }
    }
#undef ISSUE
#undef STAGE
#undef CONSUME
#undef REDUCE
}

// ---------------------------------------------------------------------------
// Epilogue: out = (concat(h_fwd, h_bwd) @ fc1 + b1) @ fc2 + b2
// ---------------------------------------------------------------------------
__global__ __launch_bounds__(64) void fc1_kernel(
    const float* __restrict__ fc1W, const float* __restrict__ fc1b,
    const float* __restrict__ Hfin, float* __restrict__ fc1out)
{
    int r = blockIdx.x;      // 0..127
    int c = threadIdx.x;     // 0..63
    const float* hf = Hfin + (size_t)r * 1024;
    const float* hb = Hfin + 131072 + (size_t)r * 1024;
    float s = fc1b[c];
    for (int k = 0; k < 1024; ++k) s += hf[k] * fc1W[k * 64 + c];
    for (int k = 0; k < 1024; ++k) s += hb[k] * fc1W[(1024 + k) * 64 + c];
    fc1out[r * 64 + c] = s;
}

__global__ __launch_bounds__(256) void fc2_kernel(
    const float* __restrict__ fc2W, const float* __restrict__ fc2b,
    const float* __restrict__ fc1out, float* __restrict__ out)
{
    int tid = threadIdx.x;   // 128 rows x 2 cols
    int r = tid >> 1, c = tid & 1;
    const float* f = fc1out + r * 64;
    float s = fc2b[c];
    for (int k = 0; k < 64; ++k) s += f[k] * fc2W[k * 2 + c];
    out[r * 2 + c] = s;
}

extern "C" void kernel_launch(void* const* d_in, const int* in_sizes, int n_in,
                              void* d_out, int out_size, void* d_ws, size_t ws_size,
                              hipStream_t stream)
{
    const int*   x    = (const int*)d_in[0];
    const float* emb  = (const float*)d_in[1];
    const float* f0Wi = (const float*)d_in[2];
    const float* f0bi = (const float*)d_in[3];
    const float* f0Wh = (const float*)d_in[4];
    const float* f0bh = (const float*)d_in[5];
    const float* f1Wi = (const float*)d_in[6];
    const float* f1bi = (const float*)d_in[7];
    const float* f1Wh = (const float*)d_in[8];
    const float* f1bh = (const float*)d_in[9];
    const float* b0Wi = (const float*)d_in[10];
    const float* b0bi = (const float*)d_in[11];
    const float* b0Wh = (const float*)d_in[12];
    const float* b0bh = (const float*)d_in[13];
    const float* b1Wi = (const float*)d_in[14];
    const float* b1bi = (const float*)d_in[15];
    const float* b1Wh = (const float*)d_in[16];
    const float* b1bh = (const float*)d_in[17];
    const float* fc1W = (const float*)d_in[18];
    const float* fc1b = (const float*)d_in[19];
    const float* fc2W = (const float*)d_in[20];
    const float* fc2b = (const float*)d_in[21];
    float* out = (float*)d_out;

    char* wsb = (char*)d_ws;
    float*          part = (float*)(wsb);
    unsigned short* Hx   = (unsigned short*)(wsb + 16777216);
    float*          Hfin = (float*)(wsb + 20971520);
    int*            tcnt = (int*)(wsb + 22020096);
    int*            xcnt = (int*)(wsb + 22022144);
    int*            dl2c = (int*)(wsb + 22022656);
    int*            dflg = (int*)(wsb + 22022784);
    int*            xcdc = (int*)(wsb + 22022912);
    float*          fc1out = (float*)(wsb + 22024192);

    // zero h state (both parities) and ALL sync/claim counters (every launch)
    hipMemsetAsync(wsb + 16777216, 0, 4194304, stream);
    hipMemsetAsync(wsb + 22020096, 0, 4096, stream);

    void* args[] = { (void*)&x, (void*)&emb,
                     (void*)&f0Wi, (void*)&f0Wh, (void*)&f1Wi, (void*)&f1Wh,
                     (void*)&b0Wi, (void*)&b0Wh, (void*)&b1Wi, (void*)&b1Wh,
                     (void*)&f0bi, (void*)&f0bh, (void*)&f1bi, (void*)&f1bh,
                     (void*)&b0bi, (void*)&b0bh, (void*)&b1bi, (void*)&b1bh,
                     (void*)&Hx, (void*)&part, (void*)&tcnt, (void*)&xcnt,
                     (void*)&dl2c, (void*)&dflg, (void*)&xcdc, (void*)&Hfin };
    hipLaunchCooperativeKernel((void*)rnn_persist, dim3(256), dim3(512),
                               args, 0, stream);

    fc1_kernel<<<128, 64, 0, stream>>>(fc1W, fc1b, Hfin, fc1out);
    fc2_kernel<<<1, 256, 0, stream>>>(fc2W, fc2b, fc1out, out);
}

// Round 17
// 7851.426 us; speedup vs baseline: 1.5835x; 1.5835x over previous
//
#include <hip/hip_runtime.h>

// BiRNN: B=128, S=512, E=512, H=1024, V=50000, C=2
// Persistent cooperative kernel, 256 blocks (1 per CU, forced by 160KB LDS).
// XCD-SELF-ORGANIZED split-K (round 12, proven): block claims a slot on its
// physical XCD; 28 roles/XCD (2 h0 tiles x 6 chunks + 2 h1 tiles x 8 chunks),
// slots 28..31 EXIT. Partials: NORMAL stores -> local L2; sc0 loads.
// Cross-XCD h state: relaxed agent-scope sc1 (LLC). Weights LDS-resident.
// Sync (round 15, proven 7.88ms):
//  - barrier-1 per TILE (fan-in 6/8): tile's chunks + partials are XCD-local
//    and self-contained; relaxed agent counter, cumulative active-epoch target
//  - barrier-2 per DIRECTION (fan-in 112): dir0 = XCDs 0-3, dir1 = XCDs 4-7
//    (mapping-guaranteed); two-level per-XCD(28) -> per-dir l2c(4) -> flag
//  - A-stage DOUBLE-BUFFERED: 8 syncs/phase (LDS = 160KiB exact)
// Round-16 nt-load experiment REVERTED (nt evicts from LLC too -> emb
// refetched from HBM every gather, FETCH 2x, dur +58%).

#define S_LEN 512

typedef short bf16x8 __attribute__((ext_vector_type(8)));
typedef float f32x4 __attribute__((ext_vector_type(4)));
typedef unsigned int u32x4 __attribute__((ext_vector_type(4)));

__device__ __forceinline__ unsigned short f2bf(float f) {
    unsigned u = __float_as_uint(f);
    u += 0x7fff + ((u >> 16) & 1);
    return (unsigned short)(u >> 16);
}
__device__ __forceinline__ float bf2f(unsigned short h) {
    return __uint_as_float(((unsigned)h) << 16);
}
__device__ __forceinline__ f32x4 mfma16(bf16x8 a, bf16x8 b, f32x4 c) {
    return __builtin_amdgcn_mfma_f32_16x16x32_bf16(a, b, c, 0, 0, 0);
}
// relaxed agent-scope (sc1 -> LLC) accesses for cross-XCD state
__device__ __forceinline__ unsigned long long ld8_cc(const void* p) {
    return __hip_atomic_load((unsigned long long*)p, __ATOMIC_RELAXED,
                             __HIP_MEMORY_SCOPE_AGENT);
}
__device__ __forceinline__ void st4_cc(void* p, float v) {
    __hip_atomic_store((int*)p, __float_as_int(v), __ATOMIC_RELAXED,
                       __HIP_MEMORY_SCOPE_AGENT);
}
// 16B sc1 store (full-line h writes, round 14). NOT compiler-tracked ->
// explicit vmcnt drain before dependent barrier (rule #18 analog).
__device__ __forceinline__ void st16_cc(void* p, u32x4 v) {
    asm volatile("global_store_dwordx4 %0, %1, off sc1"
                 :: "v"(p), "v"(v) : "memory");
}

union U8  { unsigned long long u; float f[2]; unsigned short s[4]; };
union F16 { bf16x8 v; unsigned long long u[2]; unsigned short s[8]; };

// ws layout (bytes):
//  part @ 0          : [32 tile][8 chunk][16384 f32 frag-linear] = 16,777,216
//  Hx   @ 16,777,216 : 8 slices x [128 row][128 kb][hi8|lo8] us = 4,194,304
//  Hfin @ 20,971,520 : [2 dir][128][1024] f32 = 1,048,576
//  tcnt @ 22,020,096 : 32 x 64B (per-tile barrier-1 counters)
//  xcnt @ 22,022,144 : 8 x 64B  (per-XCD barrier-2 arrivals)
//  dl2c @ 22,022,656 : 2 x 64B  (per-dir second level)
//  dflg @ 22,022,784 : 2 x 64B  (per-dir release flags)
//  xcdc @ 22,022,912 : 8 x 64B  (claim counters)
//  fc1  @ 22,024,192 : 32,768

__global__ __launch_bounds__(512) void rnn_persist(
    const int* __restrict__ x, const float* __restrict__ emb,
    const float* __restrict__ f0Wi, const float* __restrict__ f0Wh,
    const float* __restrict__ f1Wi, const float* __restrict__ f1Wh,
    const float* __restrict__ b0Wi, const float* __restrict__ b0Wh,
    const float* __restrict__ b1Wi, const float* __restrict__ b1Wh,
    const float* __restrict__ f0bi, const float* __restrict__ f0bh,
    const float* __restrict__ f1bi, const float* __restrict__ f1bh,
    const float* __restrict__ b0bi, const float* __restrict__ b0bh,
    const float* __restrict__ b1bi, const float* __restrict__ b1bh,
    unsigned short* __restrict__ Hx, float* __restrict__ part,
    int* __restrict__ tcnt, int* __restrict__ xcnt, int* __restrict__ dl2c,
    int* __restrict__ dflg, int* __restrict__ xcdc, float* __restrict__ Hfin)
{
    // LDS (ushort idx): [0,32768) W-hi  [32768,65536) W-lo  (frag order)
    //   stage buf b: hi @ 65536+b*8192, lo @ 69632+b*8192  (b=0,1)
    //   reduce bounce reuses buf0 region (first 2048 of hi/lo)
    __shared__ unsigned short lds[81920];   // 160 KiB exactly -> 1 block/CU

    const int tid = threadIdx.x;

    // ---- self-organized role claim on this block's physical XCD ----
    int xcc;
    asm volatile("s_getreg_b32 %0, hwreg(HW_REG_XCC_ID)" : "=s"(xcc));
    xcc &= 7;
    if (tid == 0)
        ((volatile int*)lds)[0] =
            __hip_atomic_fetch_add(xcdc + xcc * 16, 1,
                                   __ATOMIC_RELAXED, __HIP_MEMORY_SCOPE_AGENT);
    __syncthreads();
    const int slot = ((volatile int*)lds)[0];
    __syncthreads();            // all read slot before weights overwrite lds[0]
    if (slot >= 28) return;     // 4 idle blocks/XCD exit (barriers sized 28)

    int tileid, chunk;
    if (slot < 12) { tileid = xcc * 2 + (slot >= 6 ? 1 : 0); chunk = slot % 6; }
    else           { tileid = 16 + xcc * 2 + (slot >= 20 ? 1 : 0); chunk = (slot - 12) & 7; }
    const bool isH0 = tileid < 16;
    int dir, stripe;
    if (isH0) { dir = tileid >> 3; stripe = tileid & 7; }
    else      { int u = tileid - 16; dir = u >> 3; stripe = 8 + (u & 7); }
    const int dirg = xcc >> 2;      // barrier-2 group (== dir by mapping)

    const bool eg = isH0 && (chunk < 2);
    const int nparts = isH0 ? 6 : 8;
    const int cstart = (stripe & 7) * 128;
    const int tile = dir * 16 + stripe;
    const int hout = isH0 ? 0 : 1;

    const float* Wsrc = f0Wi; int koffw = 0; int hselA = 0;
    if (isH0) {
        if (eg) { Wsrc = dir ? b0Wi : f0Wi; koffw = chunk * 256; }
        else    { Wsrc = dir ? b0Wh : f0Wh; koffw = chunk * 256 - 512; }
    } else {
        if (chunk < 4) { Wsrc = dir ? b1Wi : f1Wi; koffw = chunk * 256;        hselA = 0; }
        else           { Wsrc = dir ? b1Wh : f1Wh; koffw = chunk * 256 - 1024; hselA = 1; }
    }
    const float *bA, *bB;
    if (isH0) { bA = dir ? b0bi : f0bi; bB = dir ? b0bh : f0bh; }
    else      { bA = dir ? b1bi : f1bi; bB = dir ? b1bh : f1bh; }

    // ---- one-time: weight tile -> LDS (hi/lo, frag order) ----
    for (int q = tid; q < 32768; q += 512) {
        int k = q >> 7, c = q & 127;
        float w = Wsrc[(size_t)(koffw + k) * 1024 + cstart + c];
        unsigned short h = f2bf(w);
        int o = ((k >> 3) * 128 + c) * 8 + (k & 7);
        lds[o] = h;
        lds[32768 + o] = f2bf(w - bf2f(h));
    }

    const int lane = tid & 63, wid = tid >> 6;
    const int wm = (wid >> 2) * 64, wn = (wid & 3) * 32;
    const int lrow = lane & 15, kgrp = lane >> 4;
    const int srow = tid >> 2;          // stager row 0..127
    const int skq  = tid & 3;           // stager k-quarter
    const int sk   = skq * 8;

    float* myPart = part + (size_t)(tile * 8 + chunk) * 16384;
    const float* pb = part + (size_t)tile * 8 * 16384;

    // reduce subtile assignment (h1: chunk<->wave; h0: 6 chunks cover 8)
    int ns, wsl0, wsl1 = 0;
    if (!isH0 || chunk < 4) { ns = 1; wsl0 = chunk; }
    else { ns = 2; wsl0 = 4 + (chunk - 4) * 2; wsl1 = wsl0 + 1; }

#define ISSUE(sl, sv)                                                          \
    do { if (eg) {                                                             \
            const float* ep_ = erow + (sv) * 32;                               \
            e0[sl] = *(const float4*)(ep_); e1[sl] = *(const float4*)(ep_ + 4);\
        } else {                                                               \
            gh[sl].u[0] = ld8_cc(aB + (sv) * 64);                              \
            gh[sl].u[1] = ld8_cc(aB + (sv) * 64 + 4);                          \
            gl[sl].u[0] = ld8_cc(aB + (sv) * 64 + 8);                          \
            gl[sl].u[1] = ld8_cc(aB + (sv) * 64 + 12);                         \
        } } while (0)

#define STAGE(sl, b)                                                           \
    do { int ao_ = (skq * 128 + srow) * 8 + (b) * 8192;                        \
        if (eg) {                                                              \
            F16 hh_, ll_;                                                      \
            float ev_[8] = {e0[sl].x, e0[sl].y, e0[sl].z, e0[sl].w,            \
                            e1[sl].x, e1[sl].y, e1[sl].z, e1[sl].w};           \
            _Pragma("unroll") for (int j_ = 0; j_ < 8; ++j_) {                 \
                unsigned short h_ = f2bf(ev_[j_]);                             \
                hh_.s[j_] = h_; ll_.s[j_] = f2bf(ev_[j_] - bf2f(h_)); }        \
            *(bf16x8*)&lds[65536 + ao_] = hh_.v;                               \
            *(bf16x8*)&lds[69632 + ao_] = ll_.v;                               \
        } else {                                                               \
            *(bf16x8*)&lds[65536 + ao_] = gh[sl].v;                            \
            *(bf16x8*)&lds[69632 + ao_] = gl[sl].v; } } while (0)

#define CONSUME(sv, b)                                                         \
    do { bf16x8 bh_[2], bl_[2];                                                \
        _Pragma("unroll") for (int jj_ = 0; jj_ < 2; ++jj_) {                  \
            int bo_ = (((sv) * 4 + kgrp) * 128 + wn + jj_ * 16 + lrow) * 8;    \
            bh_[jj_] = *(const bf16x8*)&lds[bo_];                              \
            bl_[jj_] = *(const bf16x8*)&lds[32768 + bo_]; }                    \
        _Pragma("unroll") for (int i_ = 0; i_ < 4; ++i_) {                     \
            int ao_ = (kgrp * 128 + wm + i_ * 16 + lrow) * 8 + (b) * 8192;     \
            bf16x8 ah_ = *(const bf16x8*)&lds[65536 + ao_];                    \
            bf16x8 al_ = *(const bf16x8*)&lds[69632 + ao_];                    \
            _Pragma("unroll") for (int jj_ = 0; jj_ < 2; ++jj_) {              \
                acc[i_][jj_] = mfma16(ah_, bh_[jj_], acc[i_][jj_]);            \
                acc[i_][jj_] = mfma16(ah_, bl_[jj_], acc[i_][jj_]);            \
                acc[i_][jj_] = mfma16(al_, bh_[jj_], acc[i_][jj_]); } } } while (0)

// partials are XCD-local: sc0 loads (L1-bypass, L2-served) see the dirty L2
// lines written by same-XCD producers (proven round 12).
// h store: one 16B sc1 store/thread, lane-consecutive (round 14).
#define REDUCE(NP)                                                             \
    do { unsigned short* dst = Hx + (size_t)((hout * 2 + dir) * 2 + wp) * 262144; \
        unsigned short* bh = &lds[65536];                                      \
        unsigned short* bl = &lds[69632];                                      \
        for (int si = 0; si < ns; ++si) {                                      \
            int ws_ = si ? wsl1 : wsl0;                                        \
            int q = ws_ * 512 + tid;                                           \
            const float* p0 = pb + (size_t)q * 4;                              \
            float4 pv[NP];                                                     \
            _Pragma("unroll") for (int c_ = 0; c_ < (NP); ++c_)                \
                asm volatile("global_load_dwordx4 %0, %1, off sc0"             \
                             : "=v"(pv[c_])                                    \
                             : "v"(p0 + (size_t)c_ * 16384) : "memory");       \
            asm volatile("s_waitcnt vmcnt(0)" ::: "memory");                   \
            __builtin_amdgcn_sched_barrier(0);                                 \
            float s0 = 0.f, s1 = 0.f, s2 = 0.f, s3 = 0.f;                      \
            _Pragma("unroll") for (int c_ = 0; c_ < (NP); ++c_) {              \
                s0 += pv[c_].x; s1 += pv[c_].y;                                \
                s2 += pv[c_].z; s3 += pv[c_].w; }                              \
            int t_ = ws_ * 8 + (tid >> 6);                                     \
            int ii_ = (t_ & 7) >> 1, jj_ = t_ & 1, ln_ = tid & 63;             \
            int colj = jj_ * 16 + (ln_ & 15);                                  \
            int gc = cstart + (ws_ & 3) * 32 + colj;                           \
            float bsum = bA[gc] + bB[gc];                                      \
            int rsb = ii_ * 16 + (ln_ >> 4) * 4;                               \
            float vv_[4] = {s0 + bsum, s1 + bsum, s2 + bsum, s3 + bsum};       \
            _Pragma("unroll") for (int r_ = 0; r_ < 4; ++r_) {                 \
                float v_ = tanhf(vv_[r_]);                                     \
                unsigned short h_ = f2bf(v_);                                  \
                bh[(rsb + r_) * 32 + colj] = h_;                               \
                bl[(rsb + r_) * 32 + colj] = f2bf(v_ - bf2f(h_));              \
                if (fin)                                                       \
                    st4_cc(Hfin + (size_t)dir * 131072 +                       \
                           (size_t)((ws_ >> 2) * 64 + rsb + r_) * 1024 + gc, v_); \
            }                                                                  \
            __syncthreads();                                                   \
            {                                                                  \
                int half_ = tid & 1, kbl_ = (tid >> 1) & 3, rs2_ = tid >> 3;   \
                int row_g = (ws_ >> 2) * 64 + rs2_;                            \
                int kb_g = ((cstart + (ws_ & 3) * 32) >> 3) + kbl_;            \
                const unsigned short* sp_ = (half_ ? bl : bh)                  \
                                          + rs2_ * 32 + kbl_ * 8;              \
                unsigned short* dp = dst + (size_t)row_g * 2048                \
                                   + kb_g * 16 + half_ * 8;                    \
                st16_cc(dp, *(const u32x4*)sp_);                               \
            }                                                                  \
            asm volatile("s_waitcnt vmcnt(0)" ::: "memory");                   \
            __syncthreads();                                                   \
        } } while (0)

    int tep = 0;                        // per-tile active-epoch (barrier-1)
    for (int p = 0; p <= S_LEN; ++p) {
        const bool act = isH0 ? (p < S_LEN) : (p > 0);
        const int rp = (p + 1) & 1, wp = p & 1;

        if (act) {
            // ---- GEMM: 128x128 tile over this block's 256-k chunk ----
            const unsigned short* aB = Hx;
            const float* erow = emb;
            if (eg) {
                int tsel = dir ? (S_LEN - 1 - p) : p;
                int idx = x[srow * S_LEN + tsel];
                erow = emb + (size_t)idx * 512 + koffw + sk;
            } else {
                aB = Hx + (size_t)((hselA * 2 + dir) * 2 + rp) * 262144
                   + (size_t)srow * 2048 + ((koffw >> 3) + skq) * 16;
            }

            f32x4 acc[4][2];
            #pragma unroll
            for (int i = 0; i < 4; ++i)
                #pragma unroll
                for (int j = 0; j < 2; ++j) acc[i][j] = (f32x4){0.f, 0.f, 0.f, 0.f};

            float4 e0[3], e1[3];
            F16 gh[3], gl[3];
            ISSUE(0, 0); ISSUE(1, 1); ISSUE(2, 2);
            #pragma unroll
            for (int s = 0; s < 8; ++s) {
                const int sl = s % 3;               // static under full unroll
                const int b  = s & 1;               // double-buffered stage
                STAGE(sl, b);                       // prev buf-b use ended at
                __syncthreads();                    //   sync(s-1) -> WAR safe
                if (s < 5) ISSUE(sl, s + 3);        // refill, 3 ahead
                CONSUME(s, b);
            }

            // frag-linear partial store, NORMAL stores -> local-XCD L2 only
            #pragma unroll
            for (int i = 0; i < 4; ++i)
                #pragma unroll
                for (int jj = 0; jj < 2; ++jj) {
                    int q = (wid * 8 + i * 2 + jj) * 64 + lane;
                    *(float4*)(myPart + (size_t)q * 4) =
                        make_float4(acc[i][jj][0], acc[i][jj][1],
                                    acc[i][jj][2], acc[i][jj][3]);
                }

            // ---- barrier-1: per-tile (fan-in nparts, agent/LLC) ----
            ++tep;
            __syncthreads();   // drains vmcnt -> partial stores committed to L2
            if (tid == 0) {
                __hip_atomic_fetch_add(tcnt + tile * 16, 1,
                                       __ATOMIC_RELAXED, __HIP_MEMORY_SCOPE_AGENT);
                while (__hip_atomic_load(tcnt + tile * 16, __ATOMIC_RELAXED,
                                         __HIP_MEMORY_SCOPE_AGENT) < tep * nparts) { }
            }
            __syncthreads();

            const bool fin = (!isH0) && (p == S_LEN);
            if (isH0) REDUCE(6); else REDUCE(8);
        }

        // ---- barrier-2: per-direction (28/XCD -> 4 XCDs -> flag) ----
        {
            const int ep2 = p + 1;
            __syncthreads();   // drains vmcnt -> sc1 h stores LLC-acked
            if (tid == 0) {
                int old = __hip_atomic_fetch_add(xcnt + xcc * 16, 1,
                                                 __ATOMIC_RELAXED,
                                                 __HIP_MEMORY_SCOPE_AGENT);
                if (old == ep2 * 28 - 1) {
                    int old2 = __hip_atomic_fetch_add(dl2c + dirg * 16, 1,
                                                      __ATOMIC_RELAXED,
                                                      __HIP_MEMORY_SCOPE_AGENT);
                    if (old2 == ep2 * 4 - 1)
                        __hip_atomic_store(dflg + dirg * 16, ep2,
                                           __ATOMIC_RELAXED,
                                           __HIP_MEMORY_SCOPE_AGENT);
                }
                while (__hip_atomic_load(dflg + dirg * 16, __ATOMIC_RELAXED,
                                         __HIP_MEMORY_SCOPE_AGENT) < ep2)
                    __builtin_amdgcn_s_sleep(1);
            }
            __syncthreads();
        }
    }
#undef ISSUE
#undef STAGE
#undef CONSUME
#undef REDUCE
}

// ---------------------------------------------------------------------------
// Epilogue: out = (concat(h_fwd, h_bwd) @ fc1 + b1) @ fc2 + b2
// ---------------------------------------------------------------------------
__global__ __launch_bounds__(64) void fc1_kernel(
    const float* __restrict__ fc1W, const float* __restrict__ fc1b,
    const float* __restrict__ Hfin, float* __restrict__ fc1out)
{
    int r = blockIdx.x;      // 0..127
    int c = threadIdx.x;     // 0..63
    const float* hf = Hfin + (size_t)r * 1024;
    const float* hb = Hfin + 131072 + (size_t)r * 1024;
    float s = fc1b[c];
    for (int k = 0; k < 1024; ++k) s += hf[k] * fc1W[k * 64 + c];
    for (int k = 0; k < 1024; ++k) s += hb[k] * fc1W[(1024 + k) * 64 + c];
    fc1out[r * 64 + c] = s;
}

__global__ __launch_bounds__(256) void fc2_kernel(
    const float* __restrict__ fc2W, const float* __restrict__ fc2b,
    const float* __restrict__ fc1out, float* __restrict__ out)
{
    int tid = threadIdx.x;   // 128 rows x 2 cols
    int r = tid >> 1, c = tid & 1;
    const float* f = fc1out + r * 64;
    float s = fc2b[c];
    for (int k = 0; k < 64; ++k) s += f[k] * fc2W[k * 2 + c];
    out[r * 2 + c] = s;
}

extern "C" void kernel_launch(void* const* d_in, const int* in_sizes, int n_in,
                              void* d_out, int out_size, void* d_ws, size_t ws_size,
                              hipStream_t stream)
{
    const int*   x    = (const int*)d_in[0];
    const float* emb  = (const float*)d_in[1];
    const float* f0Wi = (const float*)d_in[2];
    const float* f0bi = (const float*)d_in[3];
    const float* f0Wh = (const float*)d_in[4];
    const float* f0bh = (const float*)d_in[5];
    const float* f1Wi = (const float*)d_in[6];
    const float* f1bi = (const float*)d_in[7];
    const float* f1Wh = (const float*)d_in[8];
    const float* f1bh = (const float*)d_in[9];
    const float* b0Wi = (const float*)d_in[10];
    const float* b0bi = (const float*)d_in[11];
    const float* b0Wh = (const float*)d_in[12];
    const float* b0bh = (const float*)d_in[13];
    const float* b1Wi = (const float*)d_in[14];
    const float* b1bi = (const float*)d_in[15];
    const float* b1Wh = (const float*)d_in[16];
    const float* b1bh = (const float*)d_in[17];
    const float* fc1W = (const float*)d_in[18];
    const float* fc1b = (const float*)d_in[19];
    const float* fc2W = (const float*)d_in[20];
    const float* fc2b = (const float*)d_in[21];
    float* out = (float*)d_out;

    char* wsb = (char*)d_ws;
    float*          part = (float*)(wsb);
    unsigned short* Hx   = (unsigned short*)(wsb + 16777216);
    float*          Hfin = (float*)(wsb + 20971520);
    int*            tcnt = (int*)(wsb + 22020096);
    int*            xcnt = (int*)(wsb + 22022144);
    int*            dl2c = (int*)(wsb + 22022656);
    int*            dflg = (int*)(wsb + 22022784);
    int*            xcdc = (int*)(wsb + 22022912);
    float*          fc1out = (float*)(wsb + 22024192);

    // zero h state (both parities) and ALL sync/claim counters (every launch)
    hipMemsetAsync(wsb + 16777216, 0, 4194304, stream);
    hipMemsetAsync(wsb + 22020096, 0, 4096, stream);

    void* args[] = { (void*)&x, (void*)&emb,
                     (void*)&f0Wi, (void*)&f0Wh, (void*)&f1Wi, (void*)&f1Wh,
                     (void*)&b0Wi, (void*)&b0Wh, (void*)&b1Wi, (void*)&b1Wh,
                     (void*)&f0bi, (void*)&f0bh, (void*)&f1bi, (void*)&f1bh,
                     (void*)&b0bi, (void*)&b0bh, (void*)&b1bi, (void*)&b1bh,
                     (void*)&Hx, (void*)&part, (void*)&tcnt, (void*)&xcnt,
                     (void*)&dl2c, (void*)&dflg, (void*)&xcdc, (void*)&Hfin };
    hipLaunchCooperativeKernel((void*)rnn_persist, dim3(256), dim3(512),
                               args, 0, stream);

    fc1_kernel<<<128, 64, 0, stream>>>(fc1W, fc1b, Hfin, fc1out);
    fc2_kernel<<<1, 256, 0, stream>>>(fc2W, fc2b, fc1out, out);
}